// Round 12
// baseline (292.073 us; speedup 1.0000x reference)
//
#include <hip/hip_runtime.h>
#include <stdint.h>

#define B_ 8
#define N_ 2048
#define D_ 120
#define DP 128          // D padded to 128 (k-dim of MFMA)
#define QB 32           // q rows per attention block
#define MT 32           // m-tile (k/v rows per step)
#define NT (N_ / MT)    // 64 steps

typedef __attribute__((ext_vector_type(8))) short short8;
typedef __attribute__((ext_vector_type(4))) float f32x4;
typedef __attribute__((ext_vector_type(4))) float float4v;
typedef __attribute__((ext_vector_type(4))) unsigned int u32x4;
typedef unsigned short u16;
typedef unsigned int u32;

__device__ __forceinline__ u16 f2bf(float f){
    union { float f; uint32_t u; } v; v.f = f;
    uint32_t u = v.u;
    return (u16)((u + 0x7fffu + ((u >> 16) & 1u)) >> 16);
}
__device__ __forceinline__ float bf2f(u16 h){
    union { uint32_t u; float f; } v; v.u = ((uint32_t)h) << 16; return v.f;
}
__device__ __forceinline__ f32x4 mfma16(short8 a, short8 b, f32x4 c){
    return __builtin_amdgcn_mfma_f32_16x16x32_bf16(a, b, c, 0, 0, 0);
}
// LDS-only barrier: drain LDS ops, do NOT drain vmcnt.
__device__ __forceinline__ void bar_lds(){
    asm volatile("s_waitcnt lgkmcnt(0)\n\ts_barrier" ::: "memory");
}

// ---------------------------------------------------------------------------
// Kernel 0: transpose + split weights (bf16 hi/lo), zero-padded to 128x128.
// ---------------------------------------------------------------------------
__global__ void wprep(const float* __restrict__ Wq, const float* __restrict__ Wk,
                      const float* __restrict__ Wv,
                      u16* __restrict__ Wth, u16* __restrict__ Wtl){
    int p = blockIdx.x;
    const float* W = (p == 0) ? Wq : (p == 1 ? Wk : Wv);
    float scale = (p == 0) ? 0.09128709291752768f : 1.0f;  // 1/sqrt(120)
    for (int idx = threadIdx.x; idx < DP * DP; idx += blockDim.x){
        int c = idx & (DP - 1);
        int d = idx >> 7;
        float w = (c < D_ && d < D_) ? W[d * D_ + c] * scale : 0.f;
        u16 hi = f2bf(w);
        Wth[p * DP * DP + c * DP + d] = hi;
        Wtl[p * DP * DP + c * DP + d] = f2bf(w - bf2f(hi));
    }
}

// ---------------------------------------------------------------------------
// Kernel 1: projections. W (hi+lo) staged in swizzled LDS; V written
// tile-major [b][t][e][32] via LDS transpose (coalesced stores). (R8 verbatim)
// ---------------------------------------------------------------------------
__global__ __launch_bounds__(256, 2)
void proj_kernel(const float* __restrict__ x1, const float* __restrict__ x2,
                 const u16* __restrict__ Wth, const u16* __restrict__ Wtl,
                 u16* __restrict__ Qh, u16* __restrict__ Ql,
                 u16* __restrict__ Kh, u16* __restrict__ Kl,
                 u16* __restrict__ Vt){
    __shared__ short8 smem8[4096];          // 64 KB: WH[2048] | WL[2048]
    short8* WHs = smem8;
    short8* WLs = smem8 + 2048;
    u16* vtl = (u16*)smem8;                 // reused after compute: [128][64]

    int p    = blockIdx.y;
    const float* x = (p == 0) ? x1 : x2;
    int tid  = threadIdx.x;
    int wave = tid >> 6, lane = tid & 63;
    int g = lane >> 4, ln = lane & 15;
    long arow = (long)blockIdx.x * 64 + wave * 16 + ln;

    const u16* wh = Wth + p * DP * DP;
    const u16* wl = Wtl + p * DP * DP;
    #pragma unroll
    for (int j = 0; j < 8; ++j){
        int u = tid + j * 256;
        int row = u >> 4, cu = u & 15;
        int slot = row * 16 + (cu ^ (row & 7));
        WHs[slot] = *(const short8*)(wh + (long)u * 8);
        WLs[slot] = *(const short8*)(wl + (long)u * 8);
    }

    short8 ah[4], al[4];
    #pragma unroll
    for (int ks = 0; ks < 4; ++ks){
        int d0 = ks * 32 + g * 8;
        float xv[8];
        if (d0 < D_){
            float4v v0 = *(const float4v*)(x + arow * D_ + d0);
            float4v v1 = *(const float4v*)(x + arow * D_ + d0 + 4);
            xv[0]=v0[0]; xv[1]=v0[1]; xv[2]=v0[2]; xv[3]=v0[3];
            xv[4]=v1[0]; xv[5]=v1[1]; xv[6]=v1[2]; xv[7]=v1[3];
        } else {
            #pragma unroll
            for (int j = 0; j < 8; ++j) xv[j] = 0.f;
        }
        short8 h, l;
        #pragma unroll
        for (int j = 0; j < 8; ++j){
            u16 hb = f2bf(xv[j]);
            h[j] = (short)hb;
            l[j] = (short)f2bf(xv[j] - bf2f(hb));
        }
        ah[ks] = h; al[ks] = l;
    }
    __syncthreads();

    f32x4 acc[8];
    #pragma unroll
    for (int cf = 0; cf < 8; ++cf){
        f32x4 s0 = {0.f,0.f,0.f,0.f}, s1 = {0.f,0.f,0.f,0.f}, s2 = {0.f,0.f,0.f,0.f};
        int rbase = (cf * 16 + ln) * 16;
        #pragma unroll
        for (int ks = 0; ks < 4; ++ks){
            int cu = (ks * 4 + g) ^ (ln & 7);
            short8 bh = WHs[rbase + cu];
            short8 bl = WLs[rbase + cu];
            s0 = mfma16(ah[ks], bh, s0);
            s1 = mfma16(al[ks], bh, s1);
            s2 = mfma16(ah[ks], bl, s2);
        }
        acc[cf] = s0 + s1 + s2;
    }

    if (p < 2){
        #pragma unroll
        for (int cf = 0; cf < 8; ++cf){
            #pragma unroll
            for (int i = 0; i < 4; ++i){
                long orow = (long)blockIdx.x * 64 + wave * 16 + g * 4 + i;
                int  c    = cf * 16 + ln;
                float v   = acc[cf][i];
                u16 hb = f2bf(v);
                if (p == 0){
                    Qh[orow * DP + c] = hb;
                    Ql[orow * DP + c] = f2bf(v - bf2f(hb));
                } else {
                    Kh[orow * DP + c] = hb;
                    Kl[orow * DP + c] = f2bf(v - bf2f(hb));
                }
            }
        }
    } else {
        __syncthreads();
        #pragma unroll
        for (int cf = 0; cf < 8; ++cf){
            #pragma unroll
            for (int i = 0; i < 4; ++i){
                int c    = cf * 16 + ln;
                int lrow = wave * 16 + g * 4 + i;
                vtl[c * 64 + lrow] = f2bf(acc[cf][i]);
            }
        }
        __syncthreads();
        int c = tid >> 1, half = tid & 1;
        long n0 = ((long)blockIdx.x * 64) & 2047;
        long bb = ((long)blockIdx.x * 64) >> 11;
        long tbase = ((bb * 64 + (n0 >> 5) + half) * 128 + c) * 32;
        #pragma unroll
        for (int j = 0; j < 4; ++j){
            short8 v = *(const short8*)&vtl[c * 64 + half * 32 + j * 8];
            *(short8*)(Vt + tbase + j * 8) = v;
        }
    }
}

// ---------------------------------------------------------------------------
// Kernel 2: fused attention.
// Pass A (R8 structure): QK^T once, coalesced LDS-staged mask (raw ints,
// double-buffered, 2-deep prefetch), online (max,l); masked S (f32, -3e38
// sentinel) stored into the attnw buffer (4x 64B-segment stores/tile/wave).
// Pass B: stream S back (prefetched, coalesced), P = exp(S-M)*invL written
// in-place (coalesced), PV from Ps LDS + Vs LDS. No K staging, no QK^T
// recompute, no mask in pass B. maskprep kernel deleted.
// ---------------------------------------------------------------------------
#define ISSUE_K(P, T) do{ long gb_ = (long)(T) * MT * DP;                         \
    P##h0 = *(const short8*)(Kbh + gb_ + (long)tid * 8);                          \
    P##h1 = *(const short8*)(Kbh + gb_ + (long)(tid + 256) * 8);                  \
    P##l0 = *(const short8*)(Kbl + gb_ + (long)tid * 8);                          \
    P##l1 = *(const short8*)(Kbl + gb_ + (long)(tid + 256) * 8); }while(0)

#define WRITE_K(BUF, P) do{                                                       \
    KsH[BUF][slot0] = P##h0; KsH[BUF][slot1] = P##h1;                             \
    KsL[BUF][slot0] = P##l0; KsL[BUF][slot1] = P##l1; }while(0)

#define ISSUE_V(P, T) do{ const u16* vt_ = Vb + (long)(T) * 4096;                 \
    P##0 = *(const short8*)(vt_ + (long)tid * 8);                                 \
    P##1 = *(const short8*)(vt_ + (long)(tid + 256) * 8); }while(0)

#define WRITE_V(BUF, P) do{ Vs[BUF][vslot0] = P##0; Vs[BUF][vslot1] = P##1; }while(0)

#define ISSUE_M(P, T) do{ P = *(const u32x4*)(mptr + (long)(T) * MT); }while(0)
#define WRITE_M(BUF, P) do{ *(u32x4*)&Msk[BUF][mrow_s][mswz] = P; }while(0)

#define COMPUTE_S(CB, SD) do{                                                     \
    f32x4 s0_ = {0.f,0.f,0.f,0.f}, s1_ = s0_, s2_ = s0_;                          \
    __builtin_amdgcn_s_setprio(1);                                                \
    _Pragma("unroll") for (int ks_ = 0; ks_ < 4; ++ks_){                          \
        int cu_ = (ks_ * 4 + g) ^ swz;                                            \
        short8 bh_ = KsH[CB][mrow * 16 + cu_];                                    \
        short8 bl_ = KsL[CB][mrow * 16 + cu_];                                    \
        s0_ = mfma16(ah[ks_], bh_, s0_);                                          \
        s1_ = mfma16(al[ks_], bh_, s1_);                                          \
        s2_ = mfma16(ah[ks_], bl_, s2_); }                                        \
    __builtin_amdgcn_s_setprio(0);                                                \
    SD = s0_ + s1_ + s2_; }while(0)

// mask from LDS tile + masked-S store (attnw) + lazy online max/sum
#define AONLINE_S(BUF, T, S) do{                                                  \
    float msv_[4];                                                                \
    _Pragma("unroll") for (int i = 0; i < 4; ++i){                                \
        int rr_ = g * 4 + i;                                                      \
        u32 mk_ = Msk[BUF][rr_][mybit ^ ((rr_ & 7) << 2)];                        \
        msv_[i] = mk_ ? (S)[i] : -3.0e38f;                                        \
        attnw[ofs_[i] + (long)(T) * MT] = msv_[i]; }                              \
    _Pragma("unroll") for (int i = 0; i < 4; ++i){                                \
        float sv_ = msv_[i];                                                      \
        if (__any(sv_ > mx[i])){                                                  \
            float nm_ = fmaxf(mx[i], sv_);                                        \
            ls[i] *= __expf(mx[i] - nm_); mx[i] = nm_;                            \
        }                                                                         \
        ls[i] += __expf(sv_ - mx[i]); } }while(0)

// pass-B: consume prefetched S, P in-place + Ps LDS
#define PB_STEP(PARITY, SP, TT) do{                                               \
    f32x4 S4_ = SP;                                                               \
    if ((TT) + 2 < NT) SP = *(const f32x4*)(attnw + sofs + (long)((TT) + 2) * MT);\
    f32x4 P4_;                                                                    \
    _Pragma("unroll") for (int j = 0; j < 4; ++j)                                 \
        P4_[j] = __expf(S4_[j] - Ms) * Is;                                        \
    *(f32x4*)(attnw + sofs + (long)(TT) * MT) = P4_;                              \
    *(f32x4*)&Ps[PARITY][pslot] = P4_; }while(0)

#define PV_STEP(PB, VBUF) do{                                                     \
    int prow_ = rt * 16 + ln, sx_ = (prow_ & 7) << 2;                             \
    f32x4 pq0_ = *(const f32x4*)&Ps[PB][prow_ * 32 + ((g * 8) ^ sx_)];            \
    f32x4 pq1_ = *(const f32x4*)&Ps[PB][prow_ * 32 + (((g * 8) + 4) ^ sx_)];      \
    union { u32 w[4]; short8 s8; } pu_;                                           \
    asm("v_cvt_pk_bf16_f32 %0, %1, %2" : "=v"(pu_.w[0]) : "v"(pq0_[0]), "v"(pq0_[1])); \
    asm("v_cvt_pk_bf16_f32 %0, %1, %2" : "=v"(pu_.w[1]) : "v"(pq0_[2]), "v"(pq0_[3])); \
    asm("v_cvt_pk_bf16_f32 %0, %1, %2" : "=v"(pu_.w[2]) : "v"(pq1_[0]), "v"(pq1_[1])); \
    asm("v_cvt_pk_bf16_f32 %0, %1, %2" : "=v"(pu_.w[3]) : "v"(pq1_[2]), "v"(pq1_[3])); \
    short8 pa_ = pu_.s8;                                                          \
    __builtin_amdgcn_s_setprio(1);                                                \
    _Pragma("unroll") for (int ef_ = 0; ef_ < 4; ++ef_){                          \
        int e_ = wc * 64 + ef_ * 16 + ln;                                         \
        short8 vb_ = Vs[VBUF][e_ * 4 + (g ^ ((e_ >> 1) & 3))];                    \
        acc[ef_] = mfma16(pa_, vb_, acc[ef_]); }                                  \
    __builtin_amdgcn_s_setprio(0); }while(0)

__global__ __launch_bounds__(256, 2)
void attn_kernel(const u16* __restrict__ Qh, const u16* __restrict__ Ql,
                 const u16* __restrict__ Kh, const u16* __restrict__ Kl,
                 const u16* __restrict__ Vt, const int* __restrict__ mask,
                 float* __restrict__ outp, float* __restrict__ attnw){
    __shared__ short8 KsH[2][512];     // 16 KB [buf][32 rows x 16 units] swz
    __shared__ short8 KsL[2][512];     // 16 KB
    __shared__ short8 Vs [2][512];     // 16 KB [buf][128 e x 4 units] swz
    __shared__ float  Ps [2][QB * MT]; // 8 KB P tile, col ^ ((row&7)<<2)
    __shared__ u32    Msk[2][32][32];  // 8 KB mask tile, col4 ^ ((row&7)<<2)
    __shared__ float  redM[2][QB];
    __shared__ float  redL[2][QB];
    __shared__ float  smax[QB];
    __shared__ float  sinv[QB];

    int lin = blockIdx.x;
    int b   = lin & 7;                  // batch == XCD (round-robin dispatch)
    int q0  = (lin >> 3) * QB;
    int tid = threadIdx.x;
    int w   = tid >> 6, lane = tid & 63;
    int rt  = w & 1, wc = w >> 1;
    int g   = lane >> 4, ln = lane & 15;

    long rowbase = (long)b * N_ + q0;
    const u16* Kbh = Kh + (long)b * N_ * DP;
    const u16* Kbl = Kl + (long)b * N_ * DP;
    const u16* Vb  = Vt + ((long)b * 64) * 4096;   // tile-major: +t*4096

    // Q A-fragments
    short8 ah[4], al[4];
    {
        const u16* qh = Qh + (rowbase + rt * 16 + ln) * DP;
        const u16* ql = Ql + (rowbase + rt * 16 + ln) * DP;
        #pragma unroll
        for (int ks = 0; ks < 4; ++ks){
            ah[ks] = *(const short8*)(qh + ks * 32 + g * 8);
            al[ks] = *(const short8*)(ql + ks * 32 + g * 8);
        }
    }

    int mrow  = wc * 16 + ln;
    int swz   = ln & 7;
    int mybit = wc * 16 + ln;
    // attnw element offsets for this lane's S fragment (row g*4+i, col mybit)
    long ofs_[4];
    #pragma unroll
    for (int i = 0; i < 4; ++i)
        ofs_[i] = (rowbase + rt * 16 + g * 4 + i) * N_ + wc * 16 + ln;

    int r0 = tid >> 4,          c0 = tid & 15;
    int slot0 = r0 * 16 + (c0 ^ (r0 & 7));
    int r1 = (tid + 256) >> 4,  c1 = tid & 15;
    int slot1 = r1 * 16 + (c1 ^ (r1 & 7));
    int e0 = tid >> 2,          m0 = tid & 3;
    int vslot0 = e0 * 4 + (m0 ^ ((e0 >> 1) & 3));
    int e1 = (tid + 256) >> 2;
    int vslot1 = e1 * 4 + (m0 ^ ((e1 >> 1) & 3));

    // mask staging geometry (coalesced: 8 threads x 16B per 32-col row)
    int mrow_s = tid >> 3, c4_s = (tid & 7) * 4;
    int mswz   = c4_s ^ ((mrow_s & 7) << 2);
    const int* mptr = mask + (rowbase + mrow_s) * N_ + c4_s;

    // prefetch register sets (statically named — rule #20)
    short8 kAh0, kAh1, kAl0, kAl1;
    short8 kBh0, kBh1, kBl0, kBl1;
    short8 vA0, vA1, vB0, vB1;
    u32x4  mA, mB;

    // ================= PASS A: QK^T + online max/sum + S store =============
    float mx[4], ls[4];
    #pragma unroll
    for (int i = 0; i < 4; ++i){ mx[i] = -1e30f; ls[i] = 0.f; }

    {   // prologue: direct-stage K0/M0, prefetch K1/K2, M1/M2
        short8 h0 = *(const short8*)(Kbh + (long)tid * 8);
        short8 h1 = *(const short8*)(Kbh + (long)(tid + 256) * 8);
        short8 l0 = *(const short8*)(Kbl + (long)tid * 8);
        short8 l1 = *(const short8*)(Kbl + (long)(tid + 256) * 8);
        u32x4  m0v = *(const u32x4*)(mptr);
        ISSUE_K(kA, 1);
        ISSUE_K(kB, 2);
        ISSUE_M(mA, 1);
        ISSUE_M(mB, 2);
        KsH[0][slot0] = h0; KsH[0][slot1] = h1;
        KsL[0][slot0] = l0; KsL[0][slot1] = l1;
        *(u32x4*)&Msk[0][mrow_s][mswz] = m0v;
        bar_lds();
    }
    for (int t = 0; t < NT; t += 2){
        f32x4 s;
        COMPUTE_S(0, s);
        AONLINE_S(0, t, s);
        WRITE_K(1, kA);                       // tile t+1 (issued >=2 iters ago)
        WRITE_M(1, mA);
        if (t + 3 < NT){ ISSUE_K(kA, t + 3); ISSUE_M(mA, t + 3); }
        bar_lds();

        COMPUTE_S(1, s);
        AONLINE_S(1, t + 1, s);
        if (t + 2 < NT){ WRITE_K(0, kB); WRITE_M(0, mB); }   // tile t+2
        if (t + 4 < NT){ ISSUE_K(kB, t + 4); ISSUE_M(mB, t + 4); }
        bar_lds();
    }

    // merge across the 16 ln lanes
    #pragma unroll
    for (int i = 0; i < 4; ++i){
        #pragma unroll
        for (int sft = 1; sft < 16; sft <<= 1){
            float om = __shfl_xor(mx[i], sft, 64);
            float ol = __shfl_xor(ls[i], sft, 64);
            float nm = fmaxf(mx[i], om);
            ls[i] = ls[i] * __expf(mx[i] - nm) + ol * __expf(om - nm);
            mx[i] = nm;
        }
    }
    if (ln == 0){
        #pragma unroll
        for (int i = 0; i < 4; ++i){
            redM[wc][rt * 16 + g * 4 + i] = mx[i];
            redL[wc][rt * 16 + g * 4 + i] = ls[i];
        }
    }
    __syncthreads();
    if (tid < QB){
        float m0_ = redM[0][tid], m1_ = redM[1][tid];
        float M  = fmaxf(m0_, m1_);
        float L  = redL[0][tid] * __expf(m0_ - M) + redL[1][tid] * __expf(m1_ - M);
        smax[tid] = M;
        sinv[tid] = 1.f / L;
    }
    // S stores (pass A) must be visible to pass B loads (same block/CU)
    __threadfence();
    __syncthreads();

    // ================= PASS B: stream S -> P (in-place) + PV =================
    f32x4 acc[4];
    #pragma unroll
    for (int e = 0; e < 4; ++e) acc[e] = (f32x4){0.f, 0.f, 0.f, 0.f};

    int srow = tid >> 3, scol = (tid & 7) * 4;
    long sofs = (rowbase + srow) * N_ + scol;
    int pslot = srow * 32 + (scol ^ ((srow & 7) << 2));
    float Ms = smax[srow], Is = sinv[srow];

    f32x4 sA, sB;
    {   // prologue: prefetch S0/S1, V0/V1
        sA = *(const f32x4*)(attnw + sofs);
        sB = *(const f32x4*)(attnw + sofs + MT);
        ISSUE_V(vA, 0);
        ISSUE_V(vB, 1);
    }
    for (int t = 0; t < NT; t += 2){
        // even sub-iter: tile t
        PB_STEP(0, sA, t);
        if (t > 0) PV_STEP(1, 1);             // PV for tile t-1
        WRITE_V(0, vA);
        if (t + 2 < NT) ISSUE_V(vA, t + 2);
        bar_lds();

        // odd sub-iter: tile t+1
        PB_STEP(1, sB, t + 1);
        PV_STEP(0, 0);                        // PV for tile t
        WRITE_V(1, vB);
        if (t + 3 < NT) ISSUE_V(vB, t + 3);
        bar_lds();
    }
    PV_STEP(1, 1);                            // epilogue: tile NT-1

    // ---- output store ----
    #pragma unroll
    for (int ef = 0; ef < 4; ++ef){
        #pragma unroll
        for (int i = 0; i < 4; ++i){
            int col = wc * 64 + ef * 16 + ln;
            if (col < D_)
                outp[(rowbase + rt * 16 + g * 4 + i) * D_ + col] = acc[ef][i];
        }
    }
}

// ---------------------------------------------------------------------------
extern "C" void kernel_launch(void* const* d_in, const int* in_sizes, int n_in,
                              void* d_out, int out_size, void* d_ws, size_t ws_size,
                              hipStream_t stream){
    const float* x1   = (const float*)d_in[0];
    const float* x2   = (const float*)d_in[1];
    const int*   mask = (const int*)d_in[2];
    const float* Wq   = (const float*)d_in[3];
    const float* Wk   = (const float*)d_in[4];
    const float* Wv   = (const float*)d_in[5];

    float* outp  = (float*)d_out;
    float* attnw = outp + (size_t)B_ * N_ * D_;   // outputs concatenated flat

    const size_t TEN = (size_t)B_ * N_ * DP;      // 2,097,152
    u16* Qh   = (u16*)d_ws;
    u16* Ql   = Qh + TEN;
    u16* Kh   = Ql + TEN;
    u16* Kl   = Kh + TEN;
    u16* Vt   = Kl + TEN;                         // tile-major [B][64][128][32]
    u16* Wth  = Vt + TEN;
    u16* Wtl  = Wth + (size_t)3 * DP * DP;

    hipLaunchKernelGGL(wprep, dim3(3), dim3(256), 0, stream, Wq, Wk, Wv, Wth, Wtl);
    hipLaunchKernelGGL(proj_kernel, dim3((B_ * N_) / 64, 3), dim3(256), 0, stream,
                       x1, x2, Wth, Wtl, Qh, Ql, Kh, Kl, Vt);
    hipLaunchKernelGGL(attn_kernel, dim3((B_ * N_) / QB), dim3(256), 0, stream,
                       Qh, Ql, Kh, Kl, Vt, mask, outp, attnw);
}